// Round 10
// baseline (777.854 us; speedup 1.0000x reference)
//
#include <hip/hip_runtime.h>
#include <hip/hip_bf16.h>
#include <math.h>

#define ROWS   4096      // BATCH*SEQLEN
#define SEQLEN 2048
#define DMODEL 1024
#define DINNER 2048
#define DSSM   2016
#define NHEADS 8
#define HEADP  252
#define NPROJ  6152      // compact in_proj width: z0|x0 (4096) + xBC (2048) + dt (8)
#define LDPROJ 8200      // W_in leading dim
#define NCAT   4064      // mlp(2048) | gated y(2016)
#define NC     64        // scan chunks per sequence
#define LC     32        // chunk length = SEQLEN/NC
#define STATE  4032      // HEADP*16 state elems per (b,h)

typedef unsigned short u16;
typedef __attribute__((ext_vector_type(8))) short bf16x8;   // 8 bf16 (4 VGPRs)
typedef __attribute__((ext_vector_type(4))) float f32x4;

__device__ __forceinline__ float sigmoidf_(float x){ return 1.f/(1.f+__expf(-x)); }
__device__ __forceinline__ float siluf_(float x){ return x/(1.f+__expf(-x)); }
__device__ __forceinline__ u16 f2b(float f){ __hip_bfloat16 h = __float2bfloat16(f); return *reinterpret_cast<u16*>(&h); }
__device__ __forceinline__ float b2f(u16 s){ __hip_bfloat16 h; *reinterpret_cast<u16*>(&h)=s; return __bfloat162float(h); }

// async global->LDS, 16B per lane; LDS dest = wave-uniform base + lane*16 (m97/m104)
__device__ __forceinline__ void gload16(const u16* g, u16* l) {
  __builtin_amdgcn_global_load_lds(
      (const __attribute__((address_space(1))) void*)g,
      (__attribute__((address_space(3))) void*)l, 16, 0, 0);
}

// ---------------- f32 -> bf16 elementwise convert (for u) ----------------
__global__ __launch_bounds__(256)
void cvt_k(const float* __restrict__ in, u16* __restrict__ out, int n4)
{
  int i = blockIdx.x*256 + threadIdx.x;
  if (i >= n4) return;
  float4 v = ((const float4*)in)[i];
  ushort4 o; o.x=f2b(v.x); o.y=f2b(v.y); o.z=f2b(v.z); o.w=f2b(v.w);
  ((ushort4*)out)[i] = o;
}

// ---------------- weight transpose+convert: Wt[n][k] = bf16(W[k][remap(n)]) ----------------
template<int REMAP>
__global__ __launch_bounds__(256)
void transcvt_k(const float* __restrict__ W, u16* __restrict__ Wt,
                int K, int N, int ldw)
{
  __shared__ float t[32][33];
  const int n0 = blockIdx.x*32, k0 = blockIdx.y*32;
  const int li = threadIdx.x & 31, lj = threadIdx.x >> 5;   // lj: 0..7
  #pragma unroll
  for (int r = 0; r < 4; r++) {
    int k = k0 + lj + r*8, n = n0 + li;
    float v = 0.f;
    if (n < N) {
      int ns = REMAP ? (n < 4096 ? n : n + 2048) : n;
      v = W[(size_t)k*ldw + ns];
    }
    t[lj + r*8][li] = v;
  }
  __syncthreads();
  #pragma unroll
  for (int r = 0; r < 4; r++) {
    int n = n0 + lj + r*8, k = k0 + li;
    Wt[(size_t)n*K + k] = f2b(t[li][lj + r*8]);
  }
}

// ---------------- bf16 MFMA GEMM: C[M,N] = A[M,K] x Bt[N,K]^T ----------------
// 2-phase double-buffered (T3-minimum): 128x128 tile, 4 waves, BK=32,
// global_load_lds staging of tile t+1 issued BEFORE compute of tile t;
// one barrier per K-step (compiler emits the vmcnt(0)/lgkmcnt(0) drain).
// MODE 0: C=zx f32      MODE 1: gate — Cb[r][2048+c] = bf16(sigmoid(acc+bias[c])*bf(A[r][c]))
// MODE 2: C=out f32
template<int MODE>
__global__ __launch_bounds__(256)
void mgemm_k(const u16* __restrict__ A, const u16* __restrict__ Bt,
             float* __restrict__ Cf, u16* __restrict__ Cb,
             const float* __restrict__ bias,
             int M, int N, int K, int ldc)
{
  __shared__ __align__(16) u16 As[2][128*32];   // [buf][row][k], linear gload_lds image
  __shared__ __align__(16) u16 Bs[2][128*32];
  const int tid = threadIdx.x;
  const int lane = tid & 63, wid = tid >> 6;
  const int wr = wid >> 1, wc = wid & 1;
  const int row0 = blockIdx.y * 128, col0 = blockIdx.x * 128;
  const int lg = lane >> 4, lr = lane & 15;

  // per-lane global source: 16 rows per instr, 4 lanes/row (row=lane>>2, slot=lane&3)
  const u16* gA = A  + (size_t)(row0 + wid*32 + (lane>>2))*K + (lane&3)*8;
  const u16* gB = Bt + (size_t)(col0 + wid*32 + (lane>>2))*K + (lane&3)*8;
  const int lofs = wid*32*32;                   // wave-uniform LDS offset

  f32x4 acc[4][4];
  #pragma unroll
  for (int m=0;m<4;m++)
    #pragma unroll
    for (int n=0;n<4;n++) acc[m][n] = (f32x4){0.f,0.f,0.f,0.f};

  auto stage = [&](int buf) {
    gload16(gA,                &As[buf][lofs]);
    gload16(gA + (size_t)16*K, &As[buf][lofs + 16*32]);
    gload16(gB,                &Bs[buf][lofs]);
    gload16(gB + (size_t)16*K, &Bs[buf][lofs + 16*32]);
    gA += 32; gB += 32;
  };
  auto compute = [&](int buf) {
    bf16x8 af[4], bfr[4];
    #pragma unroll
    for (int m=0;m<4;m++) af[m]  = *(const bf16x8*)&As[buf][(wr*64 + m*16 + lr)*32 + lg*8];
    #pragma unroll
    for (int n=0;n<4;n++) bfr[n] = *(const bf16x8*)&Bs[buf][(wc*64 + n*16 + lr)*32 + lg*8];
    #pragma unroll
    for (int m=0;m<4;m++)
      #pragma unroll
      for (int n=0;n<4;n++)
        acc[m][n] = __builtin_amdgcn_mfma_f32_16x16x32_bf16(af[m], bfr[n], acc[m][n], 0, 0, 0);
  };

  const int nt = K >> 5;                        // K/32 tiles
  // prologue: stage tile 0 -> buf 0 (barrier drains vmcnt)
  stage(0);
  __syncthreads();
  int cur = 0;
  for (int t = 1; t < nt; ++t) {
    stage(cur ^ 1);      // issue next-tile loads (in flight across compute)
    compute(cur);        // ds_read + MFMA current
    __syncthreads();     // drain staged loads + all waves done reading cur
    cur ^= 1;
  }
  compute(cur);          // last tile, no prefetch

  // C/D layout (m89-verified): col = lane&15, row = (lane>>4)*4 + reg
  #pragma unroll
  for (int m=0;m<4;m++) {
    #pragma unroll
    for (int n=0;n<4;n++) {
      int colb = col0 + wc*64 + n*16 + lr;
      if (colb >= N) continue;
      #pragma unroll
      for (int r=0;r<4;r++) {
        int row = row0 + wr*64 + m*16 + lg*4 + r;
        float v = acc[m][n][r];
        if (MODE == 1) {
          v = sigmoidf_(v + bias[colb]) * b2f(A[(size_t)row*K + colb]);
          Cb[(size_t)row*NCAT + 2048 + colb] = f2b(v);
        } else {
          Cf[(size_t)row*ldc + colb] = v;
        }
      }
    }
  }
}

// ---------------- dt = softplus(dt_raw + dt_bias) ----------------
__global__ __launch_bounds__(256)
void dt_k(const float* __restrict__ zx, const float* __restrict__ dt_bias,
          float* __restrict__ dtb)
{
  int idx = blockIdx.x*256 + threadIdx.x;      // over ROWS*NHEADS
  int r = idx >> 3, hh = idx & 7;
  float v = zx[(size_t)r*NPROJ + 6144 + hh] + dt_bias[hh];
  dtb[idx] = (v > 20.f) ? v : log1pf(__expf(v));
}

// ---------------- depthwise causal conv (width 4) + SiLU ----------------
__global__ __launch_bounds__(256)
void conv_silu_k(const float* __restrict__ zx, const float* __restrict__ cw,
                 const float* __restrict__ cb, float* __restrict__ actb)
{
  int idx = blockIdx.x*256 + threadIdx.x;      // over ROWS*DINNER
  int c = idx & (DINNER-1);
  int r = idx >> 11;
  int l = r & (SEQLEN-1);
  float s = cb[c];
  #pragma unroll
  for (int k = 0; k < 4; k++) {
    int ll = l - 3 + k;
    if (ll >= 0) s += zx[(size_t)(r-3+k)*NPROJ + 4096 + c] * cw[c*4 + k];
  }
  actb[idx] = siluf_(s);
}

// ---------------- mlp_skip = silu(z0)*x0 -> bf16 into cat[:,0:2048] ----------------
__global__ __launch_bounds__(256)
void mlp_k(const float* __restrict__ zx, u16* __restrict__ cat)
{
  int idx = blockIdx.x*256 + threadIdx.x;      // over ROWS*DINNER
  int j = idx & (DINNER-1);
  int r = idx >> 11;
  float z = zx[(size_t)r*NPROJ + j];
  float x = zx[(size_t)r*NPROJ + 2048 + j];
  cat[(size_t)r*NCAT + j] = f2b(siluf_(z) * x);
}

// ================= chunk-parallel SSM scan (NC=64, LC=32) =================
// S1: per (b,h,chunk) run recurrence from h=0 -> hloc, P=exp(Ah*sum dt)
#define CH 32
__global__ __launch_bounds__(256)
void scan1_k(const float* __restrict__ actb, const float* __restrict__ dtb,
             const float* __restrict__ A_log,
             float* __restrict__ hloc, float* __restrict__ Pbuf)
{
  const int blk = blockIdx.x;            // (b*8+hh)*NC + c
  const int c = blk & (NC-1), bh = blk >> 6;
  const int hh = bh & 7, b = bh >> 3;
  const int tid = threadIdx.x;
  const float Ah = -__expf(A_log[hh]);
  float h[16];
  #pragma unroll
  for (int n = 0; n < 16; n++) h[n] = 0.f;
  float dtsum = 0.f;

  __shared__ float xs[CH][HEADP+4];
  __shared__ float bs[CH][16];
  __shared__ float dts[CH];
  const int rowbase = b*SEQLEN + c*LC;

  for (int c0 = 0; c0 < LC; c0 += CH) {
    __syncthreads();
    #pragma unroll 4
    for (int s = 0; s < CH; s++) {
      const size_t rr = (size_t)(rowbase + c0 + s) * DINNER;
      if (tid < HEADP) xs[s][tid] = actb[rr + hh*HEADP + tid];
      if (tid >= 224 && tid < 240) bs[s][tid-224] = actb[rr + DSSM + (tid-224)];
    }
    if (tid < CH) dts[tid] = dtb[(size_t)(rowbase + c0 + tid)*NHEADS + hh];
    __syncthreads();

    for (int s = 0; s < CH; s++) {
      float dtv = dts[s];
      float dA  = __expf(dtv * Ah);
      float xv  = (tid < HEADP) ? xs[s][tid] : 0.f;
      float w   = dtv * xv;
      const float4* Bp = (const float4*)&bs[s][0];
      #pragma unroll
      for (int q = 0; q < 4; q++) {
        float4 Bv = Bp[q];
        h[4*q+0] = dA*h[4*q+0] + w*Bv.x;
        h[4*q+1] = dA*h[4*q+1] + w*Bv.y;
        h[4*q+2] = dA*h[4*q+2] + w*Bv.z;
        h[4*q+3] = dA*h[4*q+3] + w*Bv.w;
      }
      dtsum += dts[s];   // uniform
    }
  }
  if (tid < HEADP) {
    float4* dst = (float4*)&hloc[((size_t)bh*NC + c)*STATE + tid*16];
    dst[0] = make_float4(h[0],h[1],h[2],h[3]);
    dst[1] = make_float4(h[4],h[5],h[6],h[7]);
    dst[2] = make_float4(h[8],h[9],h[10],h[11]);
    dst[3] = make_float4(h[12],h[13],h[14],h[15]);
  }
  if (tid == 0) Pbuf[bh*NC + c] = __expf(Ah * dtsum);
}

// S2: per (b,h) sequential combine over chunks -> Hinit[bh,c][e]
__global__ __launch_bounds__(256)
void comb_k(const float* __restrict__ hloc, const float* __restrict__ Pbuf,
            float* __restrict__ Hinit)
{
  const int bh = blockIdx.x;
  const int tid = threadIdx.x;
  __shared__ float Ps[NC];
  for (int i = tid; i < NC; i += 256) Ps[i] = Pbuf[bh*NC + i];
  __syncthreads();
  for (int e = tid; e < STATE; e += 256) {
    float H = 0.f;
    const float* hl = &hloc[(size_t)bh*NC*STATE + e];
    float* Hi = &Hinit[(size_t)bh*NC*STATE + e];
    for (int cc = 0; cc < NC; cc++) {
      Hi[(size_t)cc*STATE] = H;
      H = Ps[cc]*H + hl[(size_t)cc*STATE];
    }
  }
}

// S3: per (b,h,chunk) re-run recurrence seeded with Hinit, emit y
__global__ __launch_bounds__(256)
void scan2_k(const float* __restrict__ actb, const float* __restrict__ dtb,
             const float* __restrict__ A_log, const float* __restrict__ Dp,
             const float* __restrict__ Hinit, float* __restrict__ y)
{
  const int blk = blockIdx.x;
  const int c = blk & (NC-1), bh = blk >> 6;
  const int hh = bh & 7, b = bh >> 3;
  const int tid = threadIdx.x;
  const float Ah = -__expf(A_log[hh]);
  const float Dv = Dp[hh];
  float h[16];
  if (tid < HEADP) {
    const float4* src = (const float4*)&Hinit[((size_t)bh*NC + c)*STATE + tid*16];
    float4 a0=src[0], a1=src[1], a2=src[2], a3=src[3];
    h[0]=a0.x; h[1]=a0.y; h[2]=a0.z; h[3]=a0.w;
    h[4]=a1.x; h[5]=a1.y; h[6]=a1.z; h[7]=a1.w;
    h[8]=a2.x; h[9]=a2.y; h[10]=a2.z; h[11]=a2.w;
    h[12]=a3.x; h[13]=a3.y; h[14]=a3.z; h[15]=a3.w;
  } else {
    #pragma unroll
    for (int n = 0; n < 16; n++) h[n] = 0.f;
  }

  __shared__ float xs[CH][HEADP+4];
  __shared__ float bcs[CH][32];   // [s][0..15]=B, [s][16..31]=C
  __shared__ float dts[CH];
  const int rowbase = b*SEQLEN + c*LC;

  for (int c0 = 0; c0 < LC; c0 += CH) {
    __syncthreads();
    #pragma unroll 4
    for (int s = 0; s < CH; s++) {
      const size_t rr = (size_t)(rowbase + c0 + s) * DINNER;
      if (tid < HEADP) xs[s][tid] = actb[rr + hh*HEADP + tid];
      if (tid >= 224)  bcs[s][tid-224] = actb[rr + DSSM + (tid-224)];
    }
    if (tid < CH) dts[tid] = dtb[(size_t)(rowbase + c0 + tid)*NHEADS + hh];
    __syncthreads();

    for (int s = 0; s < CH; s++) {
      float dtv = dts[s];
      float dA  = __expf(dtv * Ah);
      float xv  = (tid < HEADP) ? xs[s][tid] : 0.f;
      float w   = dtv * xv;
      float acc = Dv * xv;
      const float4* Bp = (const float4*)&bcs[s][0];
      const float4* Cp = (const float4*)&bcs[s][16];
      #pragma unroll
      for (int q = 0; q < 4; q++) {
        float4 Bv = Bp[q], Cv = Cp[q];
        h[4*q+0] = dA*h[4*q+0] + w*Bv.x; acc += h[4*q+0]*Cv.x;
        h[4*q+1] = dA*h[4*q+1] + w*Bv.y; acc += h[4*q+1]*Cv.y;
        h[4*q+2] = dA*h[4*q+2] + w*Bv.z; acc += h[4*q+2]*Cv.z;
        h[4*q+3] = dA*h[4*q+3] + w*Bv.w; acc += h[4*q+3]*Cv.w;
      }
      if (tid < HEADP)
        y[(size_t)(rowbase + c0 + s)*DSSM + hh*HEADP + tid] = acc;
    }
  }
}

// ---------------- row LayerNorm: f32 in -> bf16 out ----------------
__global__ __launch_bounds__(256)
void ln_k(const float* __restrict__ y, const float* __restrict__ g,
          const float* __restrict__ bta, u16* __restrict__ yb)
{
  const int r = blockIdx.x;
  const int tid = threadIdx.x;
  __shared__ float r1[4], r2[4];
  __shared__ float smu, srs;
  float s1 = 0.f, s2 = 0.f;
  for (int i = tid; i < DSSM; i += 256) {
    float v = y[(size_t)r*DSSM + i];
    s1 += v; s2 += v*v;
  }
  #pragma unroll
  for (int o = 32; o > 0; o >>= 1) { s1 += __shfl_down(s1, o, 64); s2 += __shfl_down(s2, o, 64); }
  if ((tid & 63) == 0) { r1[tid>>6] = s1; r2[tid>>6] = s2; }
  __syncthreads();
  if (tid == 0) {
    float a1 = r1[0]+r1[1]+r1[2]+r1[3];
    float a2 = r2[0]+r2[1]+r2[2]+r2[3];
    float mu = a1 / (float)DSSM;
    float var = a2 / (float)DSSM - mu*mu;
    smu = mu; srs = rsqrtf(var + 1e-5f);
  }
  __syncthreads();
  float mu = smu, rs = srs;
  for (int i = tid; i < DSSM; i += 256) {
    float v = (y[(size_t)r*DSSM + i] - mu) * rs * g[i] + bta[i];
    yb[(size_t)r*DSSM + i] = f2b(v);
  }
}

extern "C" void kernel_launch(void* const* d_in, const int* in_sizes, int n_in,
                              void* d_out, int out_size, void* d_ws, size_t ws_size,
                              hipStream_t stream)
{
  const float* u      = (const float*)d_in[0];
  const float* W_in   = (const float*)d_in[1];
  const float* conv_w = (const float*)d_in[2];
  const float* conv_b = (const float*)d_in[3];
  const float* dt_bias= (const float*)d_in[4];
  const float* A_log  = (const float*)d_in[5];
  const float* Dp     = (const float*)d_in[6];
  const float* ln_g   = (const float*)d_in[7];
  const float* ln_b   = (const float*)d_in[8];
  const float* gate_w = (const float*)d_in[9];
  const float* gate_b = (const float*)d_in[10];
  const float* W_out  = (const float*)d_in[11];
  float* out = (float*)d_out;

  // ---- workspace layout (~206 MB) ----
  float* ws   = (float*)d_ws;
  float* zx   = ws;                                  // 4096 x 6152 f32
  float* actb = zx   + (size_t)ROWS*NPROJ;           // 4096 x 2048 f32
  float* dtb  = actb + (size_t)ROWS*DINNER;          // 4096 x 8 f32
  u16* u_bf   = (u16*)(dtb + (size_t)ROWS*NHEADS);   // 4096 x 1024
  u16* Wint   = u_bf  + (size_t)ROWS*DMODEL;         // 6272 x 1024
  u16* yb_bf  = Wint  + (size_t)6272*DMODEL;         // 4096 x 2016
  u16* cat_bf = yb_bf + (size_t)ROWS*DSSM;           // 4096 x 4064
  // aliases into dead zx region (zx fully consumed by dt/conv/mlp before scan)
  float* yb    = zx;                                 // 4096 x 2016 f32
  float* hloc  = zx + (size_t)ROWS*DSSM;             // 16bh x 64c x 4032 (4.13M f32)
  float* Hinit = hloc + (size_t)16*NC*STATE;         // 16bh x 64c x 4032
  float* Pbuf  = Hinit + (size_t)16*NC*STATE;        // 1024
  u16* gwt    = (u16*)actb;                          // alias: actb dead after scan
  u16* wot    = gwt + (size_t)2048*DSSM;             // 1024 x 4064

  dim3 blk(256);
  cvt_k<<<dim3((ROWS*DMODEL/4 + 255)/256), blk, 0, stream>>>(u, u_bf, ROWS*DMODEL/4);
  transcvt_k<1><<<dim3(6272/32, DMODEL/32), blk, 0, stream>>>(W_in, Wint, DMODEL, NPROJ, LDPROJ);
  // 1. in_proj GEMM
  mgemm_k<0><<<dim3(49, 32), blk, 0, stream>>>(u_bf, Wint, zx, nullptr, nullptr,
                                               ROWS, NPROJ, DMODEL, NPROJ);
  // 2-4. elementwise
  dt_k<<<dim3(ROWS*NHEADS/256), blk, 0, stream>>>(zx, dt_bias, dtb);
  conv_silu_k<<<dim3(ROWS*DINNER/256), blk, 0, stream>>>(zx, conv_w, conv_b, actb);
  mlp_k<<<dim3(ROWS*DINNER/256), blk, 0, stream>>>(zx, cat_bf);
  // 5. chunk-parallel scan: S1 local states -> S2 combine -> S3 outputs
  scan1_k<<<dim3(16*NC), blk, 0, stream>>>(actb, dtb, A_log, hloc, Pbuf);
  comb_k<<<dim3(16), blk, 0, stream>>>(hloc, Pbuf, Hinit);
  scan2_k<<<dim3(16*NC), blk, 0, stream>>>(actb, dtb, A_log, Dp, Hinit, yb);
  // 6. LayerNorm -> bf16
  ln_k<<<dim3(ROWS), blk, 0, stream>>>(yb, ln_g, ln_b, yb_bf);
  // 7. gate GEMM + fused sigmoid*y epilogue
  transcvt_k<0><<<dim3(2048/32, DSSM/32), blk, 0, stream>>>(gate_w, gwt, DSSM, DSSM, DSSM);
  mgemm_k<1><<<dim3(16, 32), blk, 0, stream>>>(yb_bf, gwt, nullptr, cat_bf, gate_b,
                                               ROWS, DSSM, DSSM, 0);
  // 8. out GEMM over materialized concat
  transcvt_k<0><<<dim3(1024/32, NCAT/32), blk, 0, stream>>>(W_out, wot, NCAT, DMODEL, DMODEL);
  mgemm_k<2><<<dim3(8, 32), blk, 0, stream>>>(cat_bf, wot, out, nullptr, nullptr,
                                              ROWS, DMODEL, NCAT, DMODEL);
}

// Round 13
// 635.708 us; speedup vs baseline: 1.2236x; 1.2236x over previous
//
#include <hip/hip_runtime.h>
#include <hip/hip_bf16.h>
#include <math.h>

#define ROWS   4096      // BATCH*SEQLEN
#define SEQLEN 2048
#define DMODEL 1024
#define DINNER 2048
#define DSSM   2016
#define NHEADS 8
#define HEADP  252
#define NPROJ  6152      // compact in_proj width: z0|x0 (4096) + xBC (2048) + dt (8)
#define LDPROJ 8200      // W_in leading dim
#define NCAT   4064      // mlp(2048) | gated y(2016)
#define NC     64        // scan chunks per sequence
#define LC     32        // chunk length = SEQLEN/NC
#define STATE  4032      // HEADP*16 state elems per (b,h)

typedef unsigned short u16;
typedef __attribute__((ext_vector_type(8))) short bf16x8;   // 8 bf16 (4 VGPRs)
typedef __attribute__((ext_vector_type(4))) float f32x4;

__device__ __forceinline__ float sigmoidf_(float x){ return 1.f/(1.f+__expf(-x)); }
__device__ __forceinline__ float siluf_(float x){ return x/(1.f+__expf(-x)); }
__device__ __forceinline__ u16 f2b(float f){ __hip_bfloat16 h = __float2bfloat16(f); return *reinterpret_cast<u16*>(&h); }
__device__ __forceinline__ float b2f(u16 s){ __hip_bfloat16 h; *reinterpret_cast<u16*>(&h)=s; return __bfloat162float(h); }

// async global->LDS, 16B per lane; LDS dest = wave-uniform base + lane*16 (m97/m104)
__device__ __forceinline__ void gload16(const u16* g, u16* l) {
  __builtin_amdgcn_global_load_lds(
      (const __attribute__((address_space(1))) void*)g,
      (__attribute__((address_space(3))) void*)l, 16, 0, 0);
}

// ---------------- f32 -> bf16 elementwise convert (for u) ----------------
__global__ __launch_bounds__(256)
void cvt_k(const float* __restrict__ in, u16* __restrict__ out, int n4)
{
  int i = blockIdx.x*256 + threadIdx.x;
  if (i >= n4) return;
  float4 v = ((const float4*)in)[i];
  ushort4 o; o.x=f2b(v.x); o.y=f2b(v.y); o.z=f2b(v.z); o.w=f2b(v.w);
  ((ushort4*)out)[i] = o;
}

// ---------------- weight transpose+convert: Wt[n][k] = bf16(W[k][remap(n)]) ----------------
template<int REMAP>
__global__ __launch_bounds__(256)
void transcvt_k(const float* __restrict__ W, u16* __restrict__ Wt,
                int K, int N, int ldw)
{
  __shared__ float t[32][33];
  const int n0 = blockIdx.x*32, k0 = blockIdx.y*32;
  const int li = threadIdx.x & 31, lj = threadIdx.x >> 5;   // lj: 0..7
  #pragma unroll
  for (int r = 0; r < 4; r++) {
    int k = k0 + lj + r*8, n = n0 + li;
    float v = 0.f;
    if (n < N) {
      int ns = REMAP ? (n < 4096 ? n : n + 2048) : n;
      v = W[(size_t)k*ldw + ns];
    }
    t[lj + r*8][li] = v;
  }
  __syncthreads();
  #pragma unroll
  for (int r = 0; r < 4; r++) {
    int n = n0 + lj + r*8, k = k0 + li;
    Wt[(size_t)n*K + k] = f2b(t[li][lj + r*8]);
  }
}

// ---------------- bf16 MFMA GEMM: C[M,N] = A[M,K] x Bt[N,K]^T ----------------
// 2-phase double-buffered (T3-minimum): 128x128 tile, 4 waves, BK=32,
// global_load_lds staging of tile t+1 issued BEFORE compute of tile t;
// one barrier per K-step (compiler emits the vmcnt(0)/lgkmcnt(0) drain).
// MODE 0: C=zx f32      MODE 1: gate — Cb[r][2048+c] = bf16(sigmoid(acc+bias[c])*bf(A[r][c]))
// MODE 2: C=out f32
template<int MODE>
__global__ __launch_bounds__(256)
void mgemm_k(const u16* __restrict__ A, const u16* __restrict__ Bt,
             float* __restrict__ Cf, u16* __restrict__ Cb,
             const float* __restrict__ bias,
             int M, int N, int K, int ldc)
{
  __shared__ __align__(16) u16 As[2][128*32];   // [buf][row][k], linear gload_lds image
  __shared__ __align__(16) u16 Bs[2][128*32];
  const int tid = threadIdx.x;
  const int lane = tid & 63, wid = tid >> 6;
  const int wr = wid >> 1, wc = wid & 1;
  const int row0 = blockIdx.y * 128, col0 = blockIdx.x * 128;
  const int lg = lane >> 4, lr = lane & 15;

  // per-lane global source: 16 rows per instr, 4 lanes/row (row=lane>>2, slot=lane&3)
  const u16* gA = A  + (size_t)(row0 + wid*32 + (lane>>2))*K + (lane&3)*8;
  const u16* gB = Bt + (size_t)(col0 + wid*32 + (lane>>2))*K + (lane&3)*8;
  const int lofs = wid*32*32;                   // wave-uniform LDS offset

  f32x4 acc[4][4];
  #pragma unroll
  for (int m=0;m<4;m++)
    #pragma unroll
    for (int n=0;n<4;n++) acc[m][n] = (f32x4){0.f,0.f,0.f,0.f};

  auto stage = [&](int buf) {
    gload16(gA,                &As[buf][lofs]);
    gload16(gA + (size_t)16*K, &As[buf][lofs + 16*32]);
    gload16(gB,                &Bs[buf][lofs]);
    gload16(gB + (size_t)16*K, &Bs[buf][lofs + 16*32]);
    gA += 32; gB += 32;
  };
  auto compute = [&](int buf) {
    bf16x8 af[4], bfr[4];
    #pragma unroll
    for (int m=0;m<4;m++) af[m]  = *(const bf16x8*)&As[buf][(wr*64 + m*16 + lr)*32 + lg*8];
    #pragma unroll
    for (int n=0;n<4;n++) bfr[n] = *(const bf16x8*)&Bs[buf][(wc*64 + n*16 + lr)*32 + lg*8];
    #pragma unroll
    for (int m=0;m<4;m++)
      #pragma unroll
      for (int n=0;n<4;n++)
        acc[m][n] = __builtin_amdgcn_mfma_f32_16x16x32_bf16(af[m], bfr[n], acc[m][n], 0, 0, 0);
  };

  const int nt = K >> 5;                        // K/32 tiles
  // prologue: stage tile 0 -> buf 0 (barrier drains vmcnt)
  stage(0);
  __syncthreads();
  int cur = 0;
  for (int t = 1; t < nt; ++t) {
    stage(cur ^ 1);      // issue next-tile loads (in flight across compute)
    compute(cur);        // ds_read + MFMA current
    __syncthreads();     // drain staged loads + all waves done reading cur
    cur ^= 1;
  }
  compute(cur);          // last tile, no prefetch

  // C/D layout (m89-verified): col = lane&15, row = (lane>>4)*4 + reg
  #pragma unroll
  for (int m=0;m<4;m++) {
    #pragma unroll
    for (int n=0;n<4;n++) {
      int colb = col0 + wc*64 + n*16 + lr;
      if (colb >= N) continue;
      #pragma unroll
      for (int r=0;r<4;r++) {
        int row = row0 + wr*64 + m*16 + lg*4 + r;
        float v = acc[m][n][r];
        if (MODE == 1) {
          v = sigmoidf_(v + bias[colb]) * b2f(A[(size_t)row*K + colb]);
          Cb[(size_t)row*NCAT + 2048 + colb] = f2b(v);
        } else {
          Cf[(size_t)row*ldc + colb] = v;
        }
      }
    }
  }
}

// ---------------- dt = softplus(dt_raw + dt_bias) ----------------
__global__ __launch_bounds__(256)
void dt_k(const float* __restrict__ zx, const float* __restrict__ dt_bias,
          float* __restrict__ dtb)
{
  int idx = blockIdx.x*256 + threadIdx.x;      // over ROWS*NHEADS
  int r = idx >> 3, hh = idx & 7;
  float v = zx[(size_t)r*NPROJ + 6144 + hh] + dt_bias[hh];
  dtb[idx] = (v > 20.f) ? v : log1pf(__expf(v));
}

// ---------------- depthwise causal conv (width 4) + SiLU ----------------
__global__ __launch_bounds__(256)
void conv_silu_k(const float* __restrict__ zx, const float* __restrict__ cw,
                 const float* __restrict__ cb, float* __restrict__ actb)
{
  int idx = blockIdx.x*256 + threadIdx.x;      // over ROWS*DINNER
  int c = idx & (DINNER-1);
  int r = idx >> 11;
  int l = r & (SEQLEN-1);
  float s = cb[c];
  #pragma unroll
  for (int k = 0; k < 4; k++) {
    int ll = l - 3 + k;
    if (ll >= 0) s += zx[(size_t)(r-3+k)*NPROJ + 4096 + c] * cw[c*4 + k];
  }
  actb[idx] = siluf_(s);
}

// ---------------- mlp_skip = silu(z0)*x0 -> bf16 into cat[:,0:2048] ----------------
__global__ __launch_bounds__(256)
void mlp_k(const float* __restrict__ zx, u16* __restrict__ cat)
{
  int idx = blockIdx.x*256 + threadIdx.x;      // over ROWS*DINNER
  int j = idx & (DINNER-1);
  int r = idx >> 11;
  float z = zx[(size_t)r*NPROJ + j];
  float x = zx[(size_t)r*NPROJ + 2048 + j];
  cat[(size_t)r*NCAT + j] = f2b(siluf_(z) * x);
}

// ================= chunk-parallel SSM scan (NC=64, LC=32) =================
// S1: per (b,h,chunk) run recurrence from h=0 -> hloc, P=exp(Ah*sum dt)
#define CH 32
__global__ __launch_bounds__(256)
void scan1_k(const float* __restrict__ actb, const float* __restrict__ dtb,
             const float* __restrict__ A_log,
             float* __restrict__ hloc, float* __restrict__ Pbuf)
{
  const int blk = blockIdx.x;            // (b*8+hh)*NC + c
  const int c = blk & (NC-1), bh = blk >> 6;
  const int hh = bh & 7, b = bh >> 3;
  const int tid = threadIdx.x;
  const float Ah = -__expf(A_log[hh]);
  float h[16];
  #pragma unroll
  for (int n = 0; n < 16; n++) h[n] = 0.f;
  float dtsum = 0.f;

  __shared__ float xs[CH][HEADP+4];
  __shared__ float bs[CH][16];
  __shared__ float dts[CH];
  const int rowbase = b*SEQLEN + c*LC;

  for (int c0 = 0; c0 < LC; c0 += CH) {
    __syncthreads();
    #pragma unroll 4
    for (int s = 0; s < CH; s++) {
      const size_t rr = (size_t)(rowbase + c0 + s) * DINNER;
      if (tid < HEADP) xs[s][tid] = actb[rr + hh*HEADP + tid];
      if (tid >= 224 && tid < 240) bs[s][tid-224] = actb[rr + DSSM + (tid-224)];
    }
    if (tid < CH) dts[tid] = dtb[(size_t)(rowbase + c0 + tid)*NHEADS + hh];
    __syncthreads();

    for (int s = 0; s < CH; s++) {
      float dtv = dts[s];
      float dA  = __expf(dtv * Ah);
      float xv  = (tid < HEADP) ? xs[s][tid] : 0.f;
      float w   = dtv * xv;
      const float4* Bp = (const float4*)&bs[s][0];
      #pragma unroll
      for (int q = 0; q < 4; q++) {
        float4 Bv = Bp[q];
        h[4*q+0] = dA*h[4*q+0] + w*Bv.x;
        h[4*q+1] = dA*h[4*q+1] + w*Bv.y;
        h[4*q+2] = dA*h[4*q+2] + w*Bv.z;
        h[4*q+3] = dA*h[4*q+3] + w*Bv.w;
      }
      dtsum += dts[s];   // uniform
    }
  }
  if (tid < HEADP) {
    float4* dst = (float4*)&hloc[((size_t)bh*NC + c)*STATE + tid*16];
    dst[0] = make_float4(h[0],h[1],h[2],h[3]);
    dst[1] = make_float4(h[4],h[5],h[6],h[7]);
    dst[2] = make_float4(h[8],h[9],h[10],h[11]);
    dst[3] = make_float4(h[12],h[13],h[14],h[15]);
  }
  if (tid == 0) Pbuf[bh*NC + c] = __expf(Ah * dtsum);
}

// S2: chunk-state combine, parallelized over e: grid = 16 bh x 16 e-chunks.
// Per-thread 64-step sequential chain (the algorithm); TLP across 256 blocks
// hides the strided-load latency that serialized the 16-block version.
__global__ __launch_bounds__(256)
void comb_k(const float* __restrict__ hloc, const float* __restrict__ Pbuf,
            float* __restrict__ Hinit)
{
  const int bh = blockIdx.x >> 4;
  const int ec = blockIdx.x & 15;
  const int tid = threadIdx.x;
  __shared__ float Ps[NC];
  for (int i = tid; i < NC; i += 256) Ps[i] = Pbuf[bh*NC + i];
  __syncthreads();
  if (tid >= 252) return;
  const int e = ec*252 + tid;            // 16 x 252 = 4032 = STATE
  float H = 0.f;
  const float* hl = &hloc[(size_t)bh*NC*STATE + e];
  float* Hi = &Hinit[(size_t)bh*NC*STATE + e];
  for (int cc = 0; cc < NC; cc++) {
    Hi[(size_t)cc*STATE] = H;
    H = Ps[cc]*H + hl[(size_t)cc*STATE];
  }
}

// S3: per (b,h,chunk) re-run recurrence seeded with Hinit, emit y
__global__ __launch_bounds__(256)
void scan2_k(const float* __restrict__ actb, const float* __restrict__ dtb,
             const float* __restrict__ A_log, const float* __restrict__ Dp,
             const float* __restrict__ Hinit, float* __restrict__ y)
{
  const int blk = blockIdx.x;
  const int c = blk & (NC-1), bh = blk >> 6;
  const int hh = bh & 7, b = bh >> 3;
  const int tid = threadIdx.x;
  const float Ah = -__expf(A_log[hh]);
  const float Dv = Dp[hh];
  float h[16];
  if (tid < HEADP) {
    const float4* src = (const float4*)&Hinit[((size_t)bh*NC + c)*STATE + tid*16];
    float4 a0=src[0], a1=src[1], a2=src[2], a3=src[3];
    h[0]=a0.x; h[1]=a0.y; h[2]=a0.z; h[3]=a0.w;
    h[4]=a1.x; h[5]=a1.y; h[6]=a1.z; h[7]=a1.w;
    h[8]=a2.x; h[9]=a2.y; h[10]=a2.z; h[11]=a2.w;
    h[12]=a3.x; h[13]=a3.y; h[14]=a3.z; h[15]=a3.w;
  } else {
    #pragma unroll
    for (int n = 0; n < 16; n++) h[n] = 0.f;
  }

  __shared__ float xs[CH][HEADP+4];
  __shared__ float bcs[CH][32];   // [s][0..15]=B, [s][16..31]=C
  __shared__ float dts[CH];
  const int rowbase = b*SEQLEN + c*LC;

  for (int c0 = 0; c0 < LC; c0 += CH) {
    __syncthreads();
    #pragma unroll 4
    for (int s = 0; s < CH; s++) {
      const size_t rr = (size_t)(rowbase + c0 + s) * DINNER;
      if (tid < HEADP) xs[s][tid] = actb[rr + hh*HEADP + tid];
      if (tid >= 224)  bcs[s][tid-224] = actb[rr + DSSM + (tid-224)];
    }
    if (tid < CH) dts[tid] = dtb[(size_t)(rowbase + c0 + tid)*NHEADS + hh];
    __syncthreads();

    for (int s = 0; s < CH; s++) {
      float dtv = dts[s];
      float dA  = __expf(dtv * Ah);
      float xv  = (tid < HEADP) ? xs[s][tid] : 0.f;
      float w   = dtv * xv;
      float acc = Dv * xv;
      const float4* Bp = (const float4*)&bcs[s][0];
      const float4* Cp = (const float4*)&bcs[s][16];
      #pragma unroll
      for (int q = 0; q < 4; q++) {
        float4 Bv = Bp[q], Cv = Cp[q];
        h[4*q+0] = dA*h[4*q+0] + w*Bv.x; acc += h[4*q+0]*Cv.x;
        h[4*q+1] = dA*h[4*q+1] + w*Bv.y; acc += h[4*q+1]*Cv.y;
        h[4*q+2] = dA*h[4*q+2] + w*Bv.z; acc += h[4*q+2]*Cv.z;
        h[4*q+3] = dA*h[4*q+3] + w*Bv.w; acc += h[4*q+3]*Cv.w;
      }
      if (tid < HEADP)
        y[(size_t)(rowbase + c0 + s)*DSSM + hh*HEADP + tid] = acc;
    }
  }
}

// ---------------- row LayerNorm: f32 in -> bf16 out ----------------
__global__ __launch_bounds__(256)
void ln_k(const float* __restrict__ y, const float* __restrict__ g,
          const float* __restrict__ bta, u16* __restrict__ yb)
{
  const int r = blockIdx.x;
  const int tid = threadIdx.x;
  __shared__ float r1[4], r2[4];
  __shared__ float smu, srs;
  float s1 = 0.f, s2 = 0.f;
  for (int i = tid; i < DSSM; i += 256) {
    float v = y[(size_t)r*DSSM + i];
    s1 += v; s2 += v*v;
  }
  #pragma unroll
  for (int o = 32; o > 0; o >>= 1) { s1 += __shfl_down(s1, o, 64); s2 += __shfl_down(s2, o, 64); }
  if ((tid & 63) == 0) { r1[tid>>6] = s1; r2[tid>>6] = s2; }
  __syncthreads();
  if (tid == 0) {
    float a1 = r1[0]+r1[1]+r1[2]+r1[3];
    float a2 = r2[0]+r2[1]+r2[2]+r2[3];
    float mu = a1 / (float)DSSM;
    float var = a2 / (float)DSSM - mu*mu;
    smu = mu; srs = rsqrtf(var + 1e-5f);
  }
  __syncthreads();
  float mu = smu, rs = srs;
  for (int i = tid; i < DSSM; i += 256) {
    float v = (y[(size_t)r*DSSM + i] - mu) * rs * g[i] + bta[i];
    yb[(size_t)r*DSSM + i] = f2b(v);
  }
}

extern "C" void kernel_launch(void* const* d_in, const int* in_sizes, int n_in,
                              void* d_out, int out_size, void* d_ws, size_t ws_size,
                              hipStream_t stream)
{
  const float* u      = (const float*)d_in[0];
  const float* W_in   = (const float*)d_in[1];
  const float* conv_w = (const float*)d_in[2];
  const float* conv_b = (const float*)d_in[3];
  const float* dt_bias= (const float*)d_in[4];
  const float* A_log  = (const float*)d_in[5];
  const float* Dp     = (const float*)d_in[6];
  const float* ln_g   = (const float*)d_in[7];
  const float* ln_b   = (const float*)d_in[8];
  const float* gate_w = (const float*)d_in[9];
  const float* gate_b = (const float*)d_in[10];
  const float* W_out  = (const float*)d_in[11];
  float* out = (float*)d_out;

  // ---- workspace layout (~206 MB) ----
  float* ws   = (float*)d_ws;
  float* zx   = ws;                                  // 4096 x 6152 f32
  float* actb = zx   + (size_t)ROWS*NPROJ;           // 4096 x 2048 f32
  float* dtb  = actb + (size_t)ROWS*DINNER;          // 4096 x 8 f32
  u16* u_bf   = (u16*)(dtb + (size_t)ROWS*NHEADS);   // 4096 x 1024
  u16* Wint   = u_bf  + (size_t)ROWS*DMODEL;         // 6272 x 1024
  u16* yb_bf  = Wint  + (size_t)6272*DMODEL;         // 4096 x 2016
  u16* cat_bf = yb_bf + (size_t)ROWS*DSSM;           // 4096 x 4064
  // aliases into dead zx region (zx fully consumed by dt/conv/mlp before scan)
  float* yb    = zx;                                 // 4096 x 2016 f32
  float* hloc  = zx + (size_t)ROWS*DSSM;             // 16bh x 64c x 4032 (4.13M f32)
  float* Hinit = hloc + (size_t)16*NC*STATE;         // 16bh x 64c x 4032
  float* Pbuf  = Hinit + (size_t)16*NC*STATE;        // 1024
  u16* gwt    = (u16*)actb;                          // alias: actb dead after scan
  u16* wot    = gwt + (size_t)2048*DSSM;             // 1024 x 4064

  dim3 blk(256);
  cvt_k<<<dim3((ROWS*DMODEL/4 + 255)/256), blk, 0, stream>>>(u, u_bf, ROWS*DMODEL/4);
  transcvt_k<1><<<dim3(6272/32, DMODEL/32), blk, 0, stream>>>(W_in, Wint, DMODEL, NPROJ, LDPROJ);
  // 1. in_proj GEMM
  mgemm_k<0><<<dim3(49, 32), blk, 0, stream>>>(u_bf, Wint, zx, nullptr, nullptr,
                                               ROWS, NPROJ, DMODEL, NPROJ);
  // 2-4. elementwise
  dt_k<<<dim3(ROWS*NHEADS/256), blk, 0, stream>>>(zx, dt_bias, dtb);
  conv_silu_k<<<dim3(ROWS*DINNER/256), blk, 0, stream>>>(zx, conv_w, conv_b, actb);
  mlp_k<<<dim3(ROWS*DINNER/256), blk, 0, stream>>>(zx, cat_bf);
  // 5. chunk-parallel scan: S1 local states -> S2 combine (16bh x 16ec) -> S3 outputs
  scan1_k<<<dim3(16*NC), blk, 0, stream>>>(actb, dtb, A_log, hloc, Pbuf);
  comb_k<<<dim3(16*16), blk, 0, stream>>>(hloc, Pbuf, Hinit);
  scan2_k<<<dim3(16*NC), blk, 0, stream>>>(actb, dtb, A_log, Dp, Hinit, yb);
  // 6. LayerNorm -> bf16
  ln_k<<<dim3(ROWS), blk, 0, stream>>>(yb, ln_g, ln_b, yb_bf);
  // 7. gate GEMM + fused sigmoid*y epilogue
  transcvt_k<0><<<dim3(2048/32, DSSM/32), blk, 0, stream>>>(gate_w, gwt, DSSM, DSSM, DSSM);
  mgemm_k<1><<<dim3(16, 32), blk, 0, stream>>>(yb_bf, gwt, nullptr, cat_bf, gate_b,
                                               ROWS, DSSM, DSSM, 0);
  // 8. out GEMM over materialized concat
  transcvt_k<0><<<dim3(1024/32, NCAT/32), blk, 0, stream>>>(W_out, wot, NCAT, DMODEL, DMODEL);
  mgemm_k<2><<<dim3(8, 32), blk, 0, stream>>>(cat_bf, wot, out, nullptr, nullptr,
                                              ROWS, DMODEL, NCAT, DMODEL);
}

// Round 14
// 625.917 us; speedup vs baseline: 1.2427x; 1.0156x over previous
//
#include <hip/hip_runtime.h>
#include <hip/hip_bf16.h>
#include <math.h>

#define ROWS   4096      // BATCH*SEQLEN
#define SEQLEN 2048
#define DMODEL 1024
#define DINNER 2048
#define DSSM   2016
#define NHEADS 8
#define HEADP  252
#define NPROJ  6152      // compact in_proj width: z0|x0 (4096) + xBC (2048) + dt (8)
#define LDPROJ 8200      // W_in leading dim
#define NCAT   4064      // mlp(2048) | gated y(2016)
#define NC     64        // scan chunks per sequence
#define LC     32        // chunk length = SEQLEN/NC
#define STATE  4032      // HEADP*16 state elems per (b,h)

typedef unsigned short u16;
typedef __attribute__((ext_vector_type(8))) short bf16x8;   // 8 bf16 (4 VGPRs)
typedef __attribute__((ext_vector_type(4))) float f32x4;

#define CFENCE asm volatile("" ::: "memory")

__device__ __forceinline__ float sigmoidf_(float x){ return 1.f/(1.f+__expf(-x)); }
__device__ __forceinline__ float siluf_(float x){ return x/(1.f+__expf(-x)); }
__device__ __forceinline__ u16 f2b(float f){ __hip_bfloat16 h = __float2bfloat16(f); return *reinterpret_cast<u16*>(&h); }
__device__ __forceinline__ float b2f(u16 s){ __hip_bfloat16 h; *reinterpret_cast<u16*>(&h)=s; return __bfloat162float(h); }

// async global->LDS, 16B per lane; LDS dest = wave-uniform base + lane*16 (m97/m104)
__device__ __forceinline__ void gload16(const u16* g, u16* l) {
  __builtin_amdgcn_global_load_lds(
      (const __attribute__((address_space(1))) void*)g,
      (__attribute__((address_space(3))) void*)l, 16, 0, 0);
}

// ---------------- f32 -> bf16 elementwise convert (for u) ----------------
__global__ __launch_bounds__(256)
void cvt_k(const float* __restrict__ in, u16* __restrict__ out, int n4)
{
  int i = blockIdx.x*256 + threadIdx.x;
  if (i >= n4) return;
  float4 v = ((const float4*)in)[i];
  ushort4 o; o.x=f2b(v.x); o.y=f2b(v.y); o.z=f2b(v.z); o.w=f2b(v.w);
  ((ushort4*)out)[i] = o;
}

// ---------------- weight transpose+convert: Wt[n][k] = bf16(W[k][remap(n)]) ----------------
template<int REMAP>
__global__ __launch_bounds__(256)
void transcvt_k(const float* __restrict__ W, u16* __restrict__ Wt,
                int K, int N, int ldw)
{
  __shared__ float t[32][33];
  const int n0 = blockIdx.x*32, k0 = blockIdx.y*32;
  const int li = threadIdx.x & 31, lj = threadIdx.x >> 5;   // lj: 0..7
  #pragma unroll
  for (int r = 0; r < 4; r++) {
    int k = k0 + lj + r*8, n = n0 + li;
    float v = 0.f;
    if (n < N) {
      int ns = REMAP ? (n < 4096 ? n : n + 2048) : n;
      v = W[(size_t)k*ldw + ns];
    }
    t[lj + r*8][li] = v;
  }
  __syncthreads();
  #pragma unroll
  for (int r = 0; r < 4; r++) {
    int n = n0 + lj + r*8, k = k0 + li;
    Wt[(size_t)n*K + k] = f2b(t[li][lj + r*8]);
  }
}

// ---------------- bf16 MFMA GEMM: C[M,N] = A[M,K] x Bt[N,K]^T ----------------
// 3-deep counted-vmcnt pipeline (T4, m218): 128x128 tile, 4 waves, BK=32,
// 3 LDS buffers; 12 global_load_lds in flight; per K-step wait vmcnt(8)
// (oldest stage only) -> raw s_barrier -> compute -> raw s_barrier -> restage.
// Loads never drain to 0 in the main loop (the m97-structure stall killer).
// MODE 0: C=zx f32      MODE 1: gate — Cb[r][2048+c] = bf16(sigmoid(acc+bias[c])*bf(A[r][c]))
// MODE 2: C=out f32
template<int MODE>
__global__ __launch_bounds__(256)
void mgemm_k(const u16* __restrict__ A, const u16* __restrict__ Bt,
             float* __restrict__ Cf, u16* __restrict__ Cb,
             const float* __restrict__ bias,
             int M, int N, int K, int ldc)
{
  __shared__ __align__(16) u16 As[3][128*32];   // [buf][row][k], linear gload_lds image
  __shared__ __align__(16) u16 Bs[3][128*32];
  const int tid = threadIdx.x;
  const int lane = tid & 63, wid = tid >> 6;
  const int wr = wid >> 1, wc = wid & 1;
  const int row0 = blockIdx.y * 128, col0 = blockIdx.x * 128;
  const int lg = lane >> 4, lr = lane & 15;

  // per-lane global source: 16 rows per instr, 4 lanes/row (row=lane>>2, slot=lane&3)
  const u16* gA = A  + (size_t)(row0 + wid*32 + (lane>>2))*K + (lane&3)*8;
  const u16* gB = Bt + (size_t)(col0 + wid*32 + (lane>>2))*K + (lane&3)*8;
  const int lofs = wid*32*32;                   // wave-uniform LDS offset

  f32x4 acc[4][4];
  #pragma unroll
  for (int m=0;m<4;m++)
    #pragma unroll
    for (int n=0;n<4;n++) acc[m][n] = (f32x4){0.f,0.f,0.f,0.f};

  auto stage = [&](int buf) {                   // 4 vmcnt events per wave
    gload16(gA,                &As[buf][lofs]);
    gload16(gA + (size_t)16*K, &As[buf][lofs + 16*32]);
    gload16(gB,                &Bs[buf][lofs]);
    gload16(gB + (size_t)16*K, &Bs[buf][lofs + 16*32]);
    gA += 32; gB += 32;
  };
  auto compute = [&](int buf) {
    bf16x8 af[4], bfr[4];
    #pragma unroll
    for (int m=0;m<4;m++) af[m]  = *(const bf16x8*)&As[buf][(wr*64 + m*16 + lr)*32 + lg*8];
    #pragma unroll
    for (int n=0;n<4;n++) bfr[n] = *(const bf16x8*)&Bs[buf][(wc*64 + n*16 + lr)*32 + lg*8];
    #pragma unroll
    for (int m=0;m<4;m++)
      #pragma unroll
      for (int n=0;n<4;n++)
        acc[m][n] = __builtin_amdgcn_mfma_f32_16x16x32_bf16(af[m], bfr[n], acc[m][n], 0, 0, 0);
  };

  const int nt = K >> 5;                        // K/32 tiles (>= 3 for all our K)
  stage(0); stage(1); stage(2);                 // tiles 0..2 -> bufs 0..2 (12 loads in flight)
  int cur = 0;
  for (int t = 0; t < nt - 2; ++t) {
    asm volatile("s_waitcnt vmcnt(8)" ::: "memory");   // oldest stage (tile t) landed
    __builtin_amdgcn_s_barrier();               // all waves' waits done -> buf readable
    CFENCE;
    compute(cur);                               // ds_read drained via MFMA data dep
    CFENCE;
    __builtin_amdgcn_s_barrier();               // all waves done reading buf
    CFENCE;
    if (t < nt - 3) stage(cur);                 // tile t+3 into freed buf
    cur = (cur == 2) ? 0 : cur + 1;
  }
  // tail: tile nt-2 (one stage still in flight behind it), then nt-1
  asm volatile("s_waitcnt vmcnt(4)" ::: "memory");
  __builtin_amdgcn_s_barrier();
  CFENCE;
  compute(cur);
  cur = (cur == 2) ? 0 : cur + 1;
  asm volatile("s_waitcnt vmcnt(0)" ::: "memory");
  __builtin_amdgcn_s_barrier();
  CFENCE;
  compute(cur);

  // C/D layout (m89-verified): col = lane&15, row = (lane>>4)*4 + reg
  #pragma unroll
  for (int m=0;m<4;m++) {
    #pragma unroll
    for (int n=0;n<4;n++) {
      int colb = col0 + wc*64 + n*16 + lr;
      if (colb >= N) continue;
      #pragma unroll
      for (int r=0;r<4;r++) {
        int row = row0 + wr*64 + m*16 + lg*4 + r;
        float v = acc[m][n][r];
        if (MODE == 1) {
          v = sigmoidf_(v + bias[colb]) * b2f(A[(size_t)row*K + colb]);
          Cb[(size_t)row*NCAT + 2048 + colb] = f2b(v);
        } else {
          Cf[(size_t)row*ldc + colb] = v;
        }
      }
    }
  }
}

// ---------------- dt = softplus(dt_raw + dt_bias) ----------------
__global__ __launch_bounds__(256)
void dt_k(const float* __restrict__ zx, const float* __restrict__ dt_bias,
          float* __restrict__ dtb)
{
  int idx = blockIdx.x*256 + threadIdx.x;      // over ROWS*NHEADS
  int r = idx >> 3, hh = idx & 7;
  float v = zx[(size_t)r*NPROJ + 6144 + hh] + dt_bias[hh];
  dtb[idx] = (v > 20.f) ? v : log1pf(__expf(v));
}

// ---------------- depthwise causal conv (width 4) + SiLU ----------------
__global__ __launch_bounds__(256)
void conv_silu_k(const float* __restrict__ zx, const float* __restrict__ cw,
                 const float* __restrict__ cb, float* __restrict__ actb)
{
  int idx = blockIdx.x*256 + threadIdx.x;      // over ROWS*DINNER
  int c = idx & (DINNER-1);
  int r = idx >> 11;
  int l = r & (SEQLEN-1);
  float s = cb[c];
  #pragma unroll
  for (int k = 0; k < 4; k++) {
    int ll = l - 3 + k;
    if (ll >= 0) s += zx[(size_t)(r-3+k)*NPROJ + 4096 + c] * cw[c*4 + k];
  }
  actb[idx] = siluf_(s);
}

// ---------------- mlp_skip = silu(z0)*x0 -> bf16 into cat[:,0:2048] ----------------
__global__ __launch_bounds__(256)
void mlp_k(const float* __restrict__ zx, u16* __restrict__ cat)
{
  int idx = blockIdx.x*256 + threadIdx.x;      // over ROWS*DINNER
  int j = idx & (DINNER-1);
  int r = idx >> 11;
  float z = zx[(size_t)r*NPROJ + j];
  float x = zx[(size_t)r*NPROJ + 2048 + j];
  cat[(size_t)r*NCAT + j] = f2b(siluf_(z) * x);
}

// ================= chunk-parallel SSM scan (NC=64, LC=32) =================
// S1: per (b,h,chunk) run recurrence from h=0 -> hloc, P=exp(Ah*sum dt)
#define CH 32
__global__ __launch_bounds__(256)
void scan1_k(const float* __restrict__ actb, const float* __restrict__ dtb,
             const float* __restrict__ A_log,
             float* __restrict__ hloc, float* __restrict__ Pbuf)
{
  const int blk = blockIdx.x;            // (b*8+hh)*NC + c
  const int c = blk & (NC-1), bh = blk >> 6;
  const int hh = bh & 7, b = bh >> 3;
  const int tid = threadIdx.x;
  const float Ah = -__expf(A_log[hh]);
  float h[16];
  #pragma unroll
  for (int n = 0; n < 16; n++) h[n] = 0.f;
  float dtsum = 0.f;

  __shared__ float xs[CH][HEADP+4];
  __shared__ float bs[CH][16];
  __shared__ float dts[CH];
  const int rowbase = b*SEQLEN + c*LC;

  for (int c0 = 0; c0 < LC; c0 += CH) {
    __syncthreads();
    #pragma unroll 4
    for (int s = 0; s < CH; s++) {
      const size_t rr = (size_t)(rowbase + c0 + s) * DINNER;
      if (tid < HEADP) xs[s][tid] = actb[rr + hh*HEADP + tid];
      if (tid >= 224 && tid < 240) bs[s][tid-224] = actb[rr + DSSM + (tid-224)];
    }
    if (tid < CH) dts[tid] = dtb[(size_t)(rowbase + c0 + tid)*NHEADS + hh];
    __syncthreads();

    for (int s = 0; s < CH; s++) {
      float dtv = dts[s];
      float dA  = __expf(dtv * Ah);
      float xv  = (tid < HEADP) ? xs[s][tid] : 0.f;
      float w   = dtv * xv;
      const float4* Bp = (const float4*)&bs[s][0];
      #pragma unroll
      for (int q = 0; q < 4; q++) {
        float4 Bv = Bp[q];
        h[4*q+0] = dA*h[4*q+0] + w*Bv.x;
        h[4*q+1] = dA*h[4*q+1] + w*Bv.y;
        h[4*q+2] = dA*h[4*q+2] + w*Bv.z;
        h[4*q+3] = dA*h[4*q+3] + w*Bv.w;
      }
      dtsum += dts[s];   // uniform
    }
  }
  if (tid < HEADP) {
    float4* dst = (float4*)&hloc[((size_t)bh*NC + c)*STATE + tid*16];
    dst[0] = make_float4(h[0],h[1],h[2],h[3]);
    dst[1] = make_float4(h[4],h[5],h[6],h[7]);
    dst[2] = make_float4(h[8],h[9],h[10],h[11]);
    dst[3] = make_float4(h[12],h[13],h[14],h[15]);
  }
  if (tid == 0) Pbuf[bh*NC + c] = __expf(Ah * dtsum);
}

// S2: chunk-state combine, parallelized over e: grid = 16 bh x 16 e-chunks.
__global__ __launch_bounds__(256)
void comb_k(const float* __restrict__ hloc, const float* __restrict__ Pbuf,
            float* __restrict__ Hinit)
{
  const int bh = blockIdx.x >> 4;
  const int ec = blockIdx.x & 15;
  const int tid = threadIdx.x;
  __shared__ float Ps[NC];
  for (int i = tid; i < NC; i += 256) Ps[i] = Pbuf[bh*NC + i];
  __syncthreads();
  if (tid >= 252) return;
  const int e = ec*252 + tid;            // 16 x 252 = 4032 = STATE
  float H = 0.f;
  const float* hl = &hloc[(size_t)bh*NC*STATE + e];
  float* Hi = &Hinit[(size_t)bh*NC*STATE + e];
  for (int cc = 0; cc < NC; cc++) {
    Hi[(size_t)cc*STATE] = H;
    H = Ps[cc]*H + hl[(size_t)cc*STATE];
  }
}

// S3: per (b,h,chunk) re-run recurrence seeded with Hinit, emit y
__global__ __launch_bounds__(256)
void scan2_k(const float* __restrict__ actb, const float* __restrict__ dtb,
             const float* __restrict__ A_log, const float* __restrict__ Dp,
             const float* __restrict__ Hinit, float* __restrict__ y)
{
  const int blk = blockIdx.x;
  const int c = blk & (NC-1), bh = blk >> 6;
  const int hh = bh & 7, b = bh >> 3;
  const int tid = threadIdx.x;
  const float Ah = -__expf(A_log[hh]);
  const float Dv = Dp[hh];
  float h[16];
  if (tid < HEADP) {
    const float4* src = (const float4*)&Hinit[((size_t)bh*NC + c)*STATE + tid*16];
    float4 a0=src[0], a1=src[1], a2=src[2], a3=src[3];
    h[0]=a0.x; h[1]=a0.y; h[2]=a0.z; h[3]=a0.w;
    h[4]=a1.x; h[5]=a1.y; h[6]=a1.z; h[7]=a1.w;
    h[8]=a2.x; h[9]=a2.y; h[10]=a2.z; h[11]=a2.w;
    h[12]=a3.x; h[13]=a3.y; h[14]=a3.z; h[15]=a3.w;
  } else {
    #pragma unroll
    for (int n = 0; n < 16; n++) h[n] = 0.f;
  }

  __shared__ float xs[CH][HEADP+4];
  __shared__ float bcs[CH][32];   // [s][0..15]=B, [s][16..31]=C
  __shared__ float dts[CH];
  const int rowbase = b*SEQLEN + c*LC;

  for (int c0 = 0; c0 < LC; c0 += CH) {
    __syncthreads();
    #pragma unroll 4
    for (int s = 0; s < CH; s++) {
      const size_t rr = (size_t)(rowbase + c0 + s) * DINNER;
      if (tid < HEADP) xs[s][tid] = actb[rr + hh*HEADP + tid];
      if (tid >= 224)  bcs[s][tid-224] = actb[rr + DSSM + (tid-224)];
    }
    if (tid < CH) dts[tid] = dtb[(size_t)(rowbase + c0 + tid)*NHEADS + hh];
    __syncthreads();

    for (int s = 0; s < CH; s++) {
      float dtv = dts[s];
      float dA  = __expf(dtv * Ah);
      float xv  = (tid < HEADP) ? xs[s][tid] : 0.f;
      float w   = dtv * xv;
      float acc = Dv * xv;
      const float4* Bp = (const float4*)&bcs[s][0];
      const float4* Cp = (const float4*)&bcs[s][16];
      #pragma unroll
      for (int q = 0; q < 4; q++) {
        float4 Bv = Bp[q], Cv = Cp[q];
        h[4*q+0] = dA*h[4*q+0] + w*Bv.x; acc += h[4*q+0]*Cv.x;
        h[4*q+1] = dA*h[4*q+1] + w*Bv.y; acc += h[4*q+1]*Cv.y;
        h[4*q+2] = dA*h[4*q+2] + w*Bv.z; acc += h[4*q+2]*Cv.z;
        h[4*q+3] = dA*h[4*q+3] + w*Bv.w; acc += h[4*q+3]*Cv.w;
      }
      if (tid < HEADP)
        y[(size_t)(rowbase + c0 + s)*DSSM + hh*HEADP + tid] = acc;
    }
  }
}

// ---------------- row LayerNorm: f32 in -> bf16 out ----------------
__global__ __launch_bounds__(256)
void ln_k(const float* __restrict__ y, const float* __restrict__ g,
          const float* __restrict__ bta, u16* __restrict__ yb)
{
  const int r = blockIdx.x;
  const int tid = threadIdx.x;
  __shared__ float r1[4], r2[4];
  __shared__ float smu, srs;
  float s1 = 0.f, s2 = 0.f;
  for (int i = tid; i < DSSM; i += 256) {
    float v = y[(size_t)r*DSSM + i];
    s1 += v; s2 += v*v;
  }
  #pragma unroll
  for (int o = 32; o > 0; o >>= 1) { s1 += __shfl_down(s1, o, 64); s2 += __shfl_down(s2, o, 64); }
  if ((tid & 63) == 0) { r1[tid>>6] = s1; r2[tid>>6] = s2; }
  __syncthreads();
  if (tid == 0) {
    float a1 = r1[0]+r1[1]+r1[2]+r1[3];
    float a2 = r2[0]+r2[1]+r2[2]+r2[3];
    float mu = a1 / (float)DSSM;
    float var = a2 / (float)DSSM - mu*mu;
    smu = mu; srs = rsqrtf(var + 1e-5f);
  }
  __syncthreads();
  float mu = smu, rs = srs;
  for (int i = tid; i < DSSM; i += 256) {
    float v = (y[(size_t)r*DSSM + i] - mu) * rs * g[i] + bta[i];
    yb[(size_t)r*DSSM + i] = f2b(v);
  }
}

extern "C" void kernel_launch(void* const* d_in, const int* in_sizes, int n_in,
                              void* d_out, int out_size, void* d_ws, size_t ws_size,
                              hipStream_t stream)
{
  const float* u      = (const float*)d_in[0];
  const float* W_in   = (const float*)d_in[1];
  const float* conv_w = (const float*)d_in[2];
  const float* conv_b = (const float*)d_in[3];
  const float* dt_bias= (const float*)d_in[4];
  const float* A_log  = (const float*)d_in[5];
  const float* Dp     = (const float*)d_in[6];
  const float* ln_g   = (const float*)d_in[7];
  const float* ln_b   = (const float*)d_in[8];
  const float* gate_w = (const float*)d_in[9];
  const float* gate_b = (const float*)d_in[10];
  const float* W_out  = (const float*)d_in[11];
  float* out = (float*)d_out;

  // ---- workspace layout (~206 MB) ----
  float* ws   = (float*)d_ws;
  float* zx   = ws;                                  // 4096 x 6152 f32
  float* actb = zx   + (size_t)ROWS*NPROJ;           // 4096 x 2048 f32
  float* dtb  = actb + (size_t)ROWS*DINNER;          // 4096 x 8 f32
  u16* u_bf   = (u16*)(dtb + (size_t)ROWS*NHEADS);   // 4096 x 1024
  u16* Wint   = u_bf  + (size_t)ROWS*DMODEL;         // 6272 x 1024
  u16* yb_bf  = Wint  + (size_t)6272*DMODEL;         // 4096 x 2016
  u16* cat_bf = yb_bf + (size_t)ROWS*DSSM;           // 4096 x 4064
  // aliases into dead zx region (zx fully consumed by dt/conv/mlp before scan)
  float* yb    = zx;                                 // 4096 x 2016 f32
  float* hloc  = zx + (size_t)ROWS*DSSM;             // 16bh x 64c x 4032 (4.13M f32)
  float* Hinit = hloc + (size_t)16*NC*STATE;         // 16bh x 64c x 4032
  float* Pbuf  = Hinit + (size_t)16*NC*STATE;        // 1024
  u16* gwt    = (u16*)actb;                          // alias: actb dead after scan
  u16* wot    = gwt + (size_t)2048*DSSM;             // 1024 x 4064

  dim3 blk(256);
  cvt_k<<<dim3((ROWS*DMODEL/4 + 255)/256), blk, 0, stream>>>(u, u_bf, ROWS*DMODEL/4);
  transcvt_k<1><<<dim3(6272/32, DMODEL/32), blk, 0, stream>>>(W_in, Wint, DMODEL, NPROJ, LDPROJ);
  // 1. in_proj GEMM
  mgemm_k<0><<<dim3(49, 32), blk, 0, stream>>>(u_bf, Wint, zx, nullptr, nullptr,
                                               ROWS, NPROJ, DMODEL, NPROJ);
  // 2-4. elementwise
  dt_k<<<dim3(ROWS*NHEADS/256), blk, 0, stream>>>(zx, dt_bias, dtb);
  conv_silu_k<<<dim3(ROWS*DINNER/256), blk, 0, stream>>>(zx, conv_w, conv_b, actb);
  mlp_k<<<dim3(ROWS*DINNER/256), blk, 0, stream>>>(zx, cat_bf);
  // 5. chunk-parallel scan: S1 local states -> S2 combine (16bh x 16ec) -> S3 outputs
  scan1_k<<<dim3(16*NC), blk, 0, stream>>>(actb, dtb, A_log, hloc, Pbuf);
  comb_k<<<dim3(16*16), blk, 0, stream>>>(hloc, Pbuf, Hinit);
  scan2_k<<<dim3(16*NC), blk, 0, stream>>>(actb, dtb, A_log, Dp, Hinit, yb);
  // 6. LayerNorm -> bf16
  ln_k<<<dim3(ROWS), blk, 0, stream>>>(yb, ln_g, ln_b, yb_bf);
  // 7. gate GEMM + fused sigmoid*y epilogue
  transcvt_k<0><<<dim3(2048/32, DSSM/32), blk, 0, stream>>>(gate_w, gwt, DSSM, DSSM, DSSM);
  mgemm_k<1><<<dim3(16, 32), blk, 0, stream>>>(yb_bf, gwt, nullptr, cat_bf, gate_b,
                                               ROWS, DSSM, DSSM, 0);
  // 8. out GEMM over materialized concat
  transcvt_k<0><<<dim3(1024/32, NCAT/32), blk, 0, stream>>>(W_out, wot, NCAT, DMODEL, DMODEL);
  mgemm_k<2><<<dim3(8, 32), blk, 0, stream>>>(cat_bf, wot, out, nullptr, nullptr,
                                              ROWS, DMODEL, NCAT, DMODEL);
}